// Round 5
// baseline (611.059 us; speedup 1.0000x reference)
//
#include <hip/hip_runtime.h>

#define NSAMP 1024
#define NC 21
#define NFG 20
#define HW 1681
#define MIN_PROB 1e-4f
#define INV_NORM (1.0f/1.0021f)   // 1 / (1 + 21*MIN_PROB)

// log-scale histogram: bin = (float_bits >> 16) - BIN_BASE
// exponent(8 bits) + 7 mantissa bits -> 0.78% bin width.
// p in [9.98e-5, 0.998] -> exponent field 113..126; base at 111 gives margin.
#define NB 2048
#define BPT 8                     // bins per thread (256 threads)
#define BIN_BASE (111 << 7)       // 14208
#define L2Q_FG (-0.0057823528f)   // log2(0.996)
#define L2Q_BG (-0.0014434217f)   // log2(0.999)

__device__ __forceinline__ float waveSum(float v) {
    #pragma unroll
    for (int o = 32; o > 0; o >>= 1) v += __shfl_down(v, o);
    return v;
}
__device__ __forceinline__ float waveMax(float v) {
    #pragma unroll
    for (int o = 32; o > 0; o >>= 1) v = fmaxf(v, __shfl_down(v, o));
    return v;
}

// K1: per-pixel log-partition-function. Only touches `output`; all 21 channel
// loads are live simultaneously (t[] needed for the max) -> MLP of 21.
__global__ __launch_bounds__(256) void kLogZ(
    const float* __restrict__ outp, float* __restrict__ logZ)
{
    const int n = blockIdx.y;
    const int pix = blockIdx.x * 256 + threadIdx.x;
    if (pix >= HW) return;
    const float* ob = outp + (size_t)n * NC * HW + pix;
    float t[NC];
    #pragma unroll
    for (int c = 0; c < NC; ++c) t[c] = ob[(size_t)c * HW];
    float m = t[0];
    #pragma unroll
    for (int c = 1; c < NC; ++c) m = fmaxf(m, t[c]);
    float S = 0.f;
    #pragma unroll
    for (int c = 0; c < NC; ++c) S += __expf(t[c] - m);
    logZ[(size_t)n * HW + pix] = m + __logf(S);
}

// kMain: one block per (n, c). PLAIN strided loop (round-2-kernelB shape --
// the compiler pipelines this well; preload arrays collapse to VGPR 20 and
// serialize, measured r3/r4). Fused in the body: loss_s partials, loss_c
// partials, channel max, packed-64-bit log-scale histogram.
__global__ __launch_bounds__(256) void kMain(
    const float* __restrict__ outp, const float* __restrict__ gt,
    const float* __restrict__ crf, const float* __restrict__ logZ,
    float* __restrict__ pm, float* __restrict__ pmx, float* __restrict__ pbg,
    float* __restrict__ samp_s, float* __restrict__ samp_cnt,
    float* __restrict__ crf_acc)
{
    __shared__ unsigned long long s_hist[NB];
    __shared__ int   s_wt[4];
    __shared__ float s_red[20];

    const int tid = threadIdx.x;
    const int n = blockIdx.x / NC;
    const int c = blockIdx.x % NC;
    const int lane = tid & 63, wid = tid >> 6;

    #pragma unroll
    for (int j = 0; j < BPT; ++j) s_hist[tid + j * 256] = 0ULL;
    __syncthreads();

    const size_t base = ((size_t)n * NC + c) * HW;
    const float* ob = outp + base;
    const float* gb = gt + base;
    const float* cb = crf + base;
    const float* lz = logZ + (size_t)n * HW;

    float maxv = 0.f, a_s = 0.f, a_cnt = 0.f, a_c = 0.f;
    for (int i = tid; i < HW; i += 256) {
        const float o  = ob[i];
        const float l  = lz[i];
        const float g  = gb[i];
        const float cr = cb[i];
        const float p  = (__expf(o - l) + MIN_PROB) * INV_NORM;
        const float lp = __logf(p);
        maxv  = fmaxf(maxv, p);
        a_s  += g * lp;
        a_cnt += g;
        a_c  += __expf(cr) * (cr - lp);
        int b = (int)(__float_as_uint(p) >> 16) - BIN_BASE;
        b = min(max(b, 0), NB - 1);
        atomicAdd(&s_hist[b], (1ULL << 44) |
                  (unsigned long long)(p * 4294967296.0f));
    }
    __syncthreads();

    // thread tid owns bins NB-1-tid*BPT-j (descending value with rising tid)
    int   cnt[BPT];
    float vs[BPT];
    int cl = 0;
    #pragma unroll
    for (int j = 0; j < BPT; ++j) {
        const unsigned long long pk = s_hist[NB - 1 - tid * BPT - j];
        cnt[j] = (int)(pk >> 44);
        vs[j]  = (float)(pk & 0xFFFFFFFFFFFULL) * (1.0f / 4294967296.0f);
        cl += cnt[j];
    }

    // exclusive prefix over tid order = # elements in strictly higher bins
    int incl = cl;
    #pragma unroll
    for (int o = 1; o < 64; o <<= 1) {
        const int u = __shfl_up(incl, o);
        if (lane >= o) incl += u;
    }
    if (lane == 63) s_wt[wid] = incl;
    __syncthreads();
    int G = incl - cl;
    for (int w = 0; w < 4; ++w) if (w < wid) G += s_wt[w];

    const float l2q = (c == 0) ? L2Q_BG : L2Q_FG;
    float contrib = 0.f;
    #pragma unroll
    for (int j = 0; j < BPT; ++j) {
        const int cb2 = cnt[j];
        if (cb2 > 0) {
            const float qg = exp2f(l2q * (float)G);
            contrib += vs[j] * qg * (1.0f - exp2f(l2q * (float)cb2)) / (float)cb2;
            G += cb2;
        }
    }

    contrib = waveSum(contrib);
    a_s = waveSum(a_s); a_cnt = waveSum(a_cnt); a_c = waveSum(a_c);
    maxv = waveMax(maxv);
    if (lane == 0) {
        s_red[wid]      = contrib;
        s_red[4 + wid]  = maxv;
        s_red[8 + wid]  = a_s;
        s_red[12 + wid] = a_cnt;
        s_red[16 + wid] = a_c;
    }
    __syncthreads();
    if (tid == 0) {
        const float total = s_red[0] + s_red[1] + s_red[2] + s_red[3];
        const float mx = fmaxf(fmaxf(s_red[4], s_red[5]), fmaxf(s_red[6], s_red[7]));
        const float ts = s_red[8] + s_red[9] + s_red[10] + s_red[11];
        const float tc = s_red[12] + s_red[13] + s_red[14] + s_red[15];
        const float tcr = s_red[16] + s_red[17] + s_red[18] + s_red[19];
        const float denom = 1.0f - exp2f(l2q * (float)HW);   // sum(w) * (1-q)
        const float mean = total / denom;
        if (c == 0) pbg[n] = mean;
        else { pm[(size_t)n * NFG + (c - 1)] = mean; pmx[(size_t)n * NFG + (c - 1)] = mx; }
        atomicAdd(&samp_s[n], ts);
        atomicAdd(&samp_cnt[n], tc);
        atomicAdd(crf_acc, tcr);
    }
}

// K3: final assembly, one sample per thread (1024 threads, 1 block).
__global__ __launch_bounds__(1024) void kernelC(
    const float* __restrict__ label, const float* __restrict__ samp_s,
    const float* __restrict__ samp_cnt, const float* __restrict__ pm,
    const float* __restrict__ pmx, const float* __restrict__ pbg,
    const float* __restrict__ crf_acc, float* __restrict__ out)
{
    const int n = threadIdx.x;
    const float v = samp_s[n] / samp_cnt[n];
    float s_stat = 0.f, l1 = 0.f, l2 = 0.f;
    #pragma unroll
    for (int c = 0; c < NFG; ++c) {
        const float st = (label[(size_t)n * NC + 1 + c] > 0.5f) ? 1.0f : 0.0f;
        s_stat += st;
        l1 += st * __logf(pm[(size_t)n * NFG + c]);
        l2 += (1.0f - st) * __logf(1.0f - pmx[(size_t)n * NFG + c]);
    }
    float acc = v + l1 / s_stat + l2 / ((float)NFG - s_stat) + __logf(pbg[n]);
    acc = waveSum(acc);
    __shared__ float s_red[16];
    const int lane = threadIdx.x & 63, wid = threadIdx.x >> 6;
    if (lane == 0) s_red[wid] = acc;
    __syncthreads();
    if (threadIdx.x == 0) {
        float tot = 0.f;
        #pragma unroll
        for (int w = 0; w < 16; ++w) tot += s_red[w];
        out[0] = -(tot / (float)NSAMP) + crf_acc[0] / ((float)NSAMP * (float)HW);
    }
}

extern "C" void kernel_launch(void* const* d_in, const int* in_sizes, int n_in,
                              void* d_out, int out_size, void* d_ws, size_t ws_size,
                              hipStream_t stream)
{
    const float* outp  = (const float*)d_in[0];
    const float* gt    = (const float*)d_in[1];
    const float* label = (const float*)d_in[2];
    const float* crf   = (const float*)d_in[3];
    float* out = (float*)d_out;

    float* ws = (float*)d_ws;
    float* samp_s   = ws;                  // 1024
    float* samp_cnt = ws + 1024;           // 1024
    float* crf_acc  = ws + 2048;           // 1 (+pad to 2064)
    float* pm   = ws + 2064;               // 1024*20
    float* pmx  = pm + NSAMP * NFG;        // 1024*20
    float* pbg  = pmx + NSAMP * NFG;       // 1024
    float* logZ = pbg + NSAMP;             // 1024*1681

    hipMemsetAsync(d_ws, 0, 2064 * sizeof(float), stream);

    dim3 grid1((HW + 255) / 256, NSAMP);
    kLogZ<<<grid1, 256, 0, stream>>>(outp, logZ);
    kMain<<<NSAMP * NC, 256, 0, stream>>>(outp, gt, crf, logZ,
                                          pm, pmx, pbg, samp_s, samp_cnt, crf_acc);
    kernelC<<<1, 1024, 0, stream>>>(label, samp_s, samp_cnt, pm, pmx, pbg, crf_acc, out);
}

// Round 6
// 525.507 us; speedup vs baseline: 1.1628x; 1.1628x over previous
//
#include <hip/hip_runtime.h>

#define NSAMP 1024
#define NC 21
#define NFG 20
#define HW 1681
#define MIN_PROB 1e-4f
#define INV_NORM (1.0f/1.0021f)   // 1 / (1 + 21*MIN_PROB)

// log-scale histogram: bin = (float_bits >> 16) - BIN_BASE (0.78% bin width)
#define NB 2048
#define BPT 8                     // bins per thread (256 threads)
#define BIN_BASE (111 << 7)       // 14208
#define L2Q_FG (-0.0057823528f)   // log2(0.996)
#define L2Q_BG (-0.0014434217f)   // log2(0.999)

#define TPX 512                   // pixels per tile in kFused
#define NT 4                      // tiles per sample: 512,512,512,145

typedef float v4u __attribute__((ext_vector_type(4), aligned(4)));   // global (rows are odd-length -> 4B align)
typedef float v4a __attribute__((ext_vector_type(4), aligned(16)));  // LDS (16B aligned by construction)

__device__ __forceinline__ float waveSum(float v) {
    #pragma unroll
    for (int o = 32; o > 0; o >>= 1) v += __shfl_down(v, o);
    return v;
}
__device__ __forceinline__ float waveMax(float v) {
    #pragma unroll
    for (int o = 32; o > 0; o >>= 1) v = fmaxf(v, __shfl_down(v, o));
    return v;
}

// kFused: one block per (tile, n). Stages output[21][512] tile to LDS with
// float4 loads (the dependent ds_write pins loads in regs -> real MLP),
// computes logZ per pixel from LDS, writes logZ, then streams gt/crf as
// float4 against LDS-resident output/logZ for loss_s / loss_c partials.
__global__ __launch_bounds__(256) void kFused(
    const float* __restrict__ outp, const float* __restrict__ gt,
    const float* __restrict__ crf, float* __restrict__ logZ,
    float* __restrict__ samp_s, float* __restrict__ samp_cnt,
    float* __restrict__ crf_acc)
{
    __shared__ float s_out[NC * TPX];   // 43008 B, rows 2048 B (16B aligned)
    __shared__ float s_lz[TPX];         // 2048 B
    __shared__ float s_red[12];

    const int tid = threadIdx.x;
    const int tile = blockIdx.x;
    const int n = blockIdx.y;
    const int pix0 = tile * TPX;
    const int npix = min(TPX, HW - pix0);
    const size_t nbase = (size_t)n * NC * HW;
    const int lane = tid & 63, wid = tid >> 6;

    // ---- phase 1: output tile -> LDS (float4) ----
    for (int s = tid; s < NC * (TPX / 4); s += 256) {
        const int c = s >> 7;           // TPX/4 = 128
        const int pr = (s & 127) * 4;   // row-relative pixel
        if (pr >= npix) continue;
        const float* src = outp + nbase + (size_t)c * HW + pix0 + pr;
        if (pr + 3 < npix) {
            *(v4a*)&s_out[c * TPX + pr] = *(const v4u*)src;
        } else {
            for (int j = 0; j < 4; ++j)
                if (pr + j < npix) s_out[c * TPX + pr + j] = src[j];
        }
    }
    __syncthreads();

    // ---- phase 2: logZ per pixel (conflict-free LDS reads) ----
    for (int p = tid; p < npix; p += 256) {
        float m = s_out[p];
        #pragma unroll
        for (int c = 1; c < NC; ++c) m = fmaxf(m, s_out[c * TPX + p]);
        float S = 0.f;
        #pragma unroll
        for (int c = 0; c < NC; ++c) S += __expf(s_out[c * TPX + p] - m);
        const float lz = m + __logf(S);
        s_lz[p] = lz;
        logZ[(size_t)n * HW + pix0 + p] = lz;
    }
    __syncthreads();

    // ---- phase 3: stream gt/crf (float4), accumulate loss_s / loss_c ----
    float a_s = 0.f, a_cnt = 0.f, a_c = 0.f;
    for (int s = tid; s < NC * (TPX / 4); s += 256) {
        const int c = s >> 7;
        const int pr = (s & 127) * 4;
        if (pr >= npix) continue;
        const size_t off = nbase + (size_t)c * HW + pix0 + pr;
        if (pr + 3 < npix) {
            const v4u g  = *(const v4u*)(gt + off);
            const v4u cr = *(const v4u*)(crf + off);
            const v4a o  = *(const v4a*)&s_out[c * TPX + pr];
            const v4a lz = *(const v4a*)&s_lz[pr];
            #pragma unroll
            for (int j = 0; j < 4; ++j) {
                const float p_ = (__expf(o[j] - lz[j]) + MIN_PROB) * INV_NORM;
                const float lp = __logf(p_);
                a_s  += g[j] * lp;
                a_cnt += g[j];
                a_c  += __expf(cr[j]) * (cr[j] - lp);
            }
        } else {
            for (int j = 0; j < 4; ++j) {
                if (pr + j < npix) {
                    const float gv = gt[off + j];
                    const float cv = crf[off + j];
                    const float p_ = (__expf(s_out[c * TPX + pr + j] - s_lz[pr + j])
                                      + MIN_PROB) * INV_NORM;
                    const float lp = __logf(p_);
                    a_s  += gv * lp;
                    a_cnt += gv;
                    a_c  += __expf(cv) * (cv - lp);
                }
            }
        }
    }

    a_s = waveSum(a_s); a_cnt = waveSum(a_cnt); a_c = waveSum(a_c);
    if (lane == 0) { s_red[wid] = a_s; s_red[4 + wid] = a_cnt; s_red[8 + wid] = a_c; }
    __syncthreads();
    if (tid == 0) {
        atomicAdd(&samp_s[n],   s_red[0] + s_red[1] + s_red[2] + s_red[3]);
        atomicAdd(&samp_cnt[n], s_red[4] + s_red[5] + s_red[6] + s_red[7]);
        atomicAdd(crf_acc,      s_red[8] + s_red[9] + s_red[10] + s_red[11]);
    }
}

// kHist: one block per (n, c). float4 loads of output/logZ, packed-64-bit
// log-scale histogram -> counting-sort GWRP + channel max. (r2-B2 scope.)
__global__ __launch_bounds__(256) void kHist(
    const float* __restrict__ outp, const float* __restrict__ logZ,
    float* __restrict__ pm, float* __restrict__ pmx, float* __restrict__ pbg)
{
    __shared__ unsigned long long s_hist[NB];
    __shared__ int   s_wt[4];
    __shared__ float s_red[8];

    const int tid = threadIdx.x;
    const int n = blockIdx.x / NC;
    const int c = blockIdx.x % NC;
    const int lane = tid & 63, wid = tid >> 6;

    #pragma unroll
    for (int j = 0; j < BPT; ++j) s_hist[tid + j * 256] = 0ULL;
    __syncthreads();

    const float* ob = outp + ((size_t)n * NC + c) * HW;
    const float* lz = logZ + (size_t)n * HW;

    float maxv = 0.f;
    for (int k = tid; k < (HW + 3) / 4; k += 256) {
        const int pr = 4 * k;
        if (pr + 3 < HW) {
            const v4u o = *(const v4u*)(ob + pr);
            const v4u l = *(const v4u*)(lz + pr);
            #pragma unroll
            for (int j = 0; j < 4; ++j) {
                const float p = (__expf(o[j] - l[j]) + MIN_PROB) * INV_NORM;
                maxv = fmaxf(maxv, p);
                int b = (int)(__float_as_uint(p) >> 16) - BIN_BASE;
                b = min(max(b, 0), NB - 1);
                atomicAdd(&s_hist[b], (1ULL << 44) |
                          (unsigned long long)(p * 4294967296.0f));
            }
        } else {
            for (int j = 0; j < 4; ++j) {
                if (pr + j < HW) {
                    const float p = (__expf(ob[pr + j] - lz[pr + j]) + MIN_PROB) * INV_NORM;
                    maxv = fmaxf(maxv, p);
                    int b = (int)(__float_as_uint(p) >> 16) - BIN_BASE;
                    b = min(max(b, 0), NB - 1);
                    atomicAdd(&s_hist[b], (1ULL << 44) |
                              (unsigned long long)(p * 4294967296.0f));
                }
            }
        }
    }
    __syncthreads();

    // thread tid owns bins NB-1-tid*BPT-j (descending value with rising tid)
    int   cnt[BPT];
    float vs[BPT];
    int cl = 0;
    #pragma unroll
    for (int j = 0; j < BPT; ++j) {
        const unsigned long long pk = s_hist[NB - 1 - tid * BPT - j];
        cnt[j] = (int)(pk >> 44);
        vs[j]  = (float)(pk & 0xFFFFFFFFFFFULL) * (1.0f / 4294967296.0f);
        cl += cnt[j];
    }

    int incl = cl;
    #pragma unroll
    for (int o = 1; o < 64; o <<= 1) {
        const int u = __shfl_up(incl, o);
        if (lane >= o) incl += u;
    }
    if (lane == 63) s_wt[wid] = incl;
    __syncthreads();
    int G = incl - cl;
    for (int w = 0; w < 4; ++w) if (w < wid) G += s_wt[w];

    const float l2q = (c == 0) ? L2Q_BG : L2Q_FG;
    float contrib = 0.f;
    #pragma unroll
    for (int j = 0; j < BPT; ++j) {
        const int cb2 = cnt[j];
        if (cb2 > 0) {
            const float qg = exp2f(l2q * (float)G);
            contrib += vs[j] * qg * (1.0f - exp2f(l2q * (float)cb2)) / (float)cb2;
            G += cb2;
        }
    }

    contrib = waveSum(contrib);
    maxv = waveMax(maxv);
    if (lane == 0) { s_red[wid] = contrib; s_red[4 + wid] = maxv; }
    __syncthreads();
    if (tid == 0) {
        const float total = s_red[0] + s_red[1] + s_red[2] + s_red[3];
        const float mx = fmaxf(fmaxf(s_red[4], s_red[5]), fmaxf(s_red[6], s_red[7]));
        const float denom = 1.0f - exp2f(l2q * (float)HW);
        const float mean = total / denom;
        if (c == 0) pbg[n] = mean;
        else { pm[(size_t)n * NFG + (c - 1)] = mean; pmx[(size_t)n * NFG + (c - 1)] = mx; }
    }
}

// kC: final assembly, one sample per thread (1024 threads, 1 block).
__global__ __launch_bounds__(1024) void kernelC(
    const float* __restrict__ label, const float* __restrict__ samp_s,
    const float* __restrict__ samp_cnt, const float* __restrict__ pm,
    const float* __restrict__ pmx, const float* __restrict__ pbg,
    const float* __restrict__ crf_acc, float* __restrict__ out)
{
    const int n = threadIdx.x;
    const float v = samp_s[n] / samp_cnt[n];
    float s_stat = 0.f, l1 = 0.f, l2 = 0.f;
    #pragma unroll
    for (int c = 0; c < NFG; ++c) {
        const float st = (label[(size_t)n * NC + 1 + c] > 0.5f) ? 1.0f : 0.0f;
        s_stat += st;
        l1 += st * __logf(pm[(size_t)n * NFG + c]);
        l2 += (1.0f - st) * __logf(1.0f - pmx[(size_t)n * NFG + c]);
    }
    float acc = v + l1 / s_stat + l2 / ((float)NFG - s_stat) + __logf(pbg[n]);
    acc = waveSum(acc);
    __shared__ float s_red[16];
    const int lane = threadIdx.x & 63, wid = threadIdx.x >> 6;
    if (lane == 0) s_red[wid] = acc;
    __syncthreads();
    if (threadIdx.x == 0) {
        float tot = 0.f;
        #pragma unroll
        for (int w = 0; w < 16; ++w) tot += s_red[w];
        out[0] = -(tot / (float)NSAMP) + crf_acc[0] / ((float)NSAMP * (float)HW);
    }
}

extern "C" void kernel_launch(void* const* d_in, const int* in_sizes, int n_in,
                              void* d_out, int out_size, void* d_ws, size_t ws_size,
                              hipStream_t stream)
{
    const float* outp  = (const float*)d_in[0];
    const float* gt    = (const float*)d_in[1];
    const float* label = (const float*)d_in[2];
    const float* crf   = (const float*)d_in[3];
    float* out = (float*)d_out;

    float* ws = (float*)d_ws;
    float* samp_s   = ws;                  // 1024
    float* samp_cnt = ws + 1024;           // 1024
    float* crf_acc  = ws + 2048;           // 1 (+pad to 2064)
    float* pm   = ws + 2064;               // 1024*20
    float* pmx  = pm + NSAMP * NFG;        // 1024*20
    float* pbg  = pmx + NSAMP * NFG;       // 1024
    float* logZ = pbg + NSAMP;             // 1024*1681

    hipMemsetAsync(d_ws, 0, 2064 * sizeof(float), stream);

    dim3 gridF(NT, NSAMP);
    kFused<<<gridF, 256, 0, stream>>>(outp, gt, crf, logZ, samp_s, samp_cnt, crf_acc);
    kHist<<<NSAMP * NC, 256, 0, stream>>>(outp, logZ, pm, pmx, pbg);
    kernelC<<<1, 1024, 0, stream>>>(label, samp_s, samp_cnt, pm, pmx, pbg, crf_acc, out);
}